// Round 13
// baseline (302.308 us; speedup 1.0000x reference)
//
#include <hip/hip_runtime.h>
#include <math.h>

#define NB   4
#define SEQ  2048
#define DM   512
#define KS   16
#define ROWS (NB*SEQ)   // 8192

#define NCHUNK 16
#define CLEN   (SEQ / NCHUNK)          // 128
#define CH_TOT (2 * NB * NCHUNK * DM * KS)   // 1,048,576 per array

typedef __attribute__((ext_vector_type(8))) short          bf16x8;
typedef __attribute__((ext_vector_type(8))) unsigned short u16x8;
typedef __attribute__((ext_vector_type(4))) float          f32x4;

__device__ __forceinline__ float softplus_f(float z) {
    return z > 20.f ? z : log1pf(__expf(z));
}

// f32 -> bf16 (RNE), bit-level (no NaN handling; inputs finite)
__device__ __forceinline__ unsigned short f2bf(float f) {
    unsigned int u = __builtin_bit_cast(unsigned int, f);
    u += 0x7fffu + ((u >> 16) & 1u);
    return (unsigned short)(u >> 16);
}

// ---------------------------------------------------------------------------
// Kernel 1: MFMA bf16 GEMM: d = softplus(toks@Wd^T + bd);
// writes PACKED float2 {delta, delta*x} to odd.
// 128x128 tile, 4 waves (2x2), wave tile 64x64, mfma_f32_16x16x32_bf16.
// Both A (toks) and B (Wd) staged f32 -> bf16 in registers (no pre-cast).
// ---------------------------------------------------------------------------
#define GBM 128
#define GBN 128
#define GBK 32
#define PADK 40

__global__ __launch_bounds__(256)
void k_gemm_delta(const float* __restrict__ toks, const float* __restrict__ Wd,
                  const float* __restrict__ bd, float* __restrict__ odd)
{
    __shared__ unsigned short As[GBM][PADK];
    __shared__ unsigned short Bs[GBN][PADK];
    const int tid = threadIdx.x;
    const int rowBase = blockIdx.x * GBM;
    const int colBase = blockIdx.y * GBN;

    const int l   = tid & 63;
    const int wid = tid >> 6;          // 0..3
    const int wm  = wid >> 1;          // 0..1
    const int wn  = wid & 1;           // 0..1
    const int lr  = l & 15;            // A row / B col / D col lane part
    const int lk  = (l >> 4) * 8;      // frag k offset (8 contiguous bf16)
    const int lq  = (l >> 4) * 4;      // D row sub-offset

    // staging: 2 threads cover one row's 32 k
    const int srow  = tid >> 1;        // 0..127
    const int skoff = (tid & 1) * 16;  // 0 / 16

    const float* gA = toks + (size_t)(rowBase + srow) * DM + skoff;
    const float* gW = Wd   + (size_t)(colBase + srow) * DM + skoff;

    const f32x4 zero4 = {0.f, 0.f, 0.f, 0.f};
    f32x4 acc[4][4];
    #pragma unroll
    for (int i = 0; i < 4; ++i)
        #pragma unroll
        for (int j = 0; j < 4; ++j) acc[i][j] = zero4;

    // prefetch tile 0
    float4 pa0 = *(const float4*)(gA);
    float4 pa1 = *(const float4*)(gA + 4);
    float4 pa2 = *(const float4*)(gA + 8);
    float4 pa3 = *(const float4*)(gA + 12);
    float4 pw0 = *(const float4*)(gW);
    float4 pw1 = *(const float4*)(gW + 4);
    float4 pw2 = *(const float4*)(gW + 8);
    float4 pw3 = *(const float4*)(gW + 12);

    for (int e0 = 0; e0 < DM; e0 += GBK) {
        __syncthreads();   // previous iteration done reading LDS
        u16x8 va, vb, vc, vd;
        va[0] = f2bf(pa0.x); va[1] = f2bf(pa0.y); va[2] = f2bf(pa0.z); va[3] = f2bf(pa0.w);
        va[4] = f2bf(pa1.x); va[5] = f2bf(pa1.y); va[6] = f2bf(pa1.z); va[7] = f2bf(pa1.w);
        vb[0] = f2bf(pa2.x); vb[1] = f2bf(pa2.y); vb[2] = f2bf(pa2.z); vb[3] = f2bf(pa2.w);
        vb[4] = f2bf(pa3.x); vb[5] = f2bf(pa3.y); vb[6] = f2bf(pa3.z); vb[7] = f2bf(pa3.w);
        vc[0] = f2bf(pw0.x); vc[1] = f2bf(pw0.y); vc[2] = f2bf(pw0.z); vc[3] = f2bf(pw0.w);
        vc[4] = f2bf(pw1.x); vc[5] = f2bf(pw1.y); vc[6] = f2bf(pw1.z); vc[7] = f2bf(pw1.w);
        vd[0] = f2bf(pw2.x); vd[1] = f2bf(pw2.y); vd[2] = f2bf(pw2.z); vd[3] = f2bf(pw2.w);
        vd[4] = f2bf(pw3.x); vd[5] = f2bf(pw3.y); vd[6] = f2bf(pw3.z); vd[7] = f2bf(pw3.w);
        *(u16x8*)&As[srow][skoff]     = va;
        *(u16x8*)&As[srow][skoff + 8] = vb;
        *(u16x8*)&Bs[srow][skoff]     = vc;
        *(u16x8*)&Bs[srow][skoff + 8] = vd;
        __syncthreads();

        // prefetch next tile; latency hides under ds_reads + 16 MFMA
        if (e0 + GBK < DM) {
            pa0 = *(const float4*)(gA + e0 + GBK);
            pa1 = *(const float4*)(gA + e0 + GBK + 4);
            pa2 = *(const float4*)(gA + e0 + GBK + 8);
            pa3 = *(const float4*)(gA + e0 + GBK + 12);
            pw0 = *(const float4*)(gW + e0 + GBK);
            pw1 = *(const float4*)(gW + e0 + GBK + 4);
            pw2 = *(const float4*)(gW + e0 + GBK + 8);
            pw3 = *(const float4*)(gW + e0 + GBK + 12);
        }

        bf16x8 af[4], bfr[4];
        #pragma unroll
        for (int f = 0; f < 4; ++f)
            af[f] = *(const bf16x8*)&As[wm * 64 + f * 16 + lr][lk];
        #pragma unroll
        for (int f = 0; f < 4; ++f)
            bfr[f] = *(const bf16x8*)&Bs[wn * 64 + f * 16 + lr][lk];

        #pragma unroll
        for (int fm = 0; fm < 4; ++fm)
            #pragma unroll
            for (int fn = 0; fn < 4; ++fn)
                acc[fm][fn] = __builtin_amdgcn_mfma_f32_16x16x32_bf16(
                    af[fm], bfr[fn], acc[fm][fn], 0, 0, 0);
    }

    // epilogue: D lane mapping row=(l>>4)*4+r, col=l&15 (m89-verified)
    // packed write: odd[2*off] = delta, odd[2*off+1] = delta*x
    #pragma unroll
    for (int fn = 0; fn < 4; ++fn) {
        const int col = colBase + wn * 64 + fn * 16 + lr;
        const float bias = bd[col];
        #pragma unroll
        for (int fm = 0; fm < 4; ++fm) {
            const int row0 = rowBase + wm * 64 + fm * 16 + lq;
            #pragma unroll
            for (int r = 0; r < 4; ++r) {
                const size_t off = (size_t)(row0 + r) * DM + col;
                const float dl = softplus_f(acc[fm][fn][r] + bias);
                *(float2*)&odd[2 * off] = make_float2(dl, dl * toks[off]);
            }
        }
    }
}

// ---------------------------------------------------------------------------
// Kernel 2: packed {B,C}: obc[2*(row*KS+k)] = toks@WB^T, +1 = toks@WC^T. f32.
// ---------------------------------------------------------------------------
__global__ __launch_bounds__(256)
void k_bc(const float* __restrict__ toks, const float* __restrict__ WB,
          const float* __restrict__ WC, float* __restrict__ obc)
{
    const int tid = threadIdx.x;
    const int k  = tid & 15;
    const int rl = tid >> 4;
    const int row = blockIdx.x * 16 + rl;
    const float* tp = toks + (size_t)row * DM;
    const float* wb = WB + (size_t)k * DM;
    const float* wc = WC + (size_t)k * DM;
    float ab = 0.f, ac = 0.f;
    #pragma unroll 4
    for (int e = 0; e < DM; e += 4) {
        float4 tv = *(const float4*)(tp + e);
        float4 bv = *(const float4*)(wb + e);
        float4 cv = *(const float4*)(wc + e);
        ab = fmaf(tv.x, bv.x, ab); ab = fmaf(tv.y, bv.y, ab);
        ab = fmaf(tv.z, bv.z, ab); ab = fmaf(tv.w, bv.w, ab);
        ac = fmaf(tv.x, cv.x, ac); ac = fmaf(tv.y, cv.y, ac);
        ac = fmaf(tv.z, cv.z, ac); ac = fmaf(tv.w, cv.w, ac);
    }
    *(float2*)&obc[2 * ((size_t)row * KS + k)] = make_float2(ab, ac);
}

// ---------------------------------------------------------------------------
// Kernel 3a: chunked scan, pass 1. Thread = (dir,n,chunk,d,k).
// Packed loads: dd = {delta, delta*x}, bc = {B, C} -> 2 x 8B per step.
// Chunk summary: h_end = P*h0 + Q ; sum_t c_t h_t = R*h0 + S.
// ---------------------------------------------------------------------------
__global__ __launch_bounds__(256)
void k_scan_chunk(const float* __restrict__ dd, const float* __restrict__ bc,
                  const float* __restrict__ logA,
                  float* __restrict__ oP, float* __restrict__ oQ,
                  float* __restrict__ oR, float* __restrict__ oS)
{
    const int g     = blockIdx.x * blockDim.x + threadIdx.x;
    const int k     = g & 15;
    const int d     = (g >> 4) & (DM - 1);
    const int chunk = (g >> 13) & (NCHUNK - 1);
    const int n     = (g >> 17) & (NB - 1);
    const int dir   = (g >> 19) & 1;

    const float Ac = -__expf(logA[d * KS + k]);

    const int sgn = dir ? -1 : 1;
    const int t0  = dir ? (SEQ - 1 - chunk * CLEN) : (chunk * CLEN);
    const size_t rbase = (size_t)n * SEQ + t0;

    const float* pd = dd + 2 * (rbase * DM + d);
    const float* pb = bc + 2 * (rbase * KS + k);
    const int sD = sgn * DM * 2;
    const int sK = sgn * KS * 2;

    float A = 1.f, u = 0.f, R = 0.f, S = 0.f;
    #pragma unroll 4
    for (int t = 0; t < CLEN; ++t) {
        const float2 v = *(const float2*)pd;   // {delta, delta*x}
        const float2 w = *(const float2*)pb;   // {B, C}
        pd += sD; pb += sK;
        const float a = __expf(v.x * Ac);
        u = fmaf(a, u, v.y * w.x);
        A = A * a;
        R = fmaf(w.y, A, R);
        S = fmaf(w.y, u, S);
    }

    const size_t idx = ((((size_t)dir * NB + n) * NCHUNK + chunk) * DM + d) * KS + k;
    oP[idx] = A; oQ[idx] = u; oR[idx] = R; oS[idx] = S;
}

// ---------------------------------------------------------------------------
// Kernel 3b: compose chunk summaries; reduce over k (4 bits) + dir (1 bit)
// in-lane via shfl_xor; lane 0 of each 32-group stores directly (no atomic).
// Thread layout: tid5 = k + 16*dir (low 5 bits), then d (9), n (2).
// ---------------------------------------------------------------------------
__global__ __launch_bounds__(256)
void k_scan_fix(const float* __restrict__ oP, const float* __restrict__ oQ,
                const float* __restrict__ oR, const float* __restrict__ oS,
                float* __restrict__ out)
{
    const int g    = blockIdx.x * blockDim.x + threadIdx.x;
    const int k    = g & 15;
    const int dir  = (g >> 4) & 1;
    const int d    = (g >> 5) & (DM - 1);
    const int n    = (g >> 14) & (NB - 1);

    size_t idx = ((((size_t)dir * NB + n) * NCHUNK) * DM + d) * KS + k;
    const size_t stride = (size_t)DM * KS;

    float h = 0.f, acc = 0.f;
    #pragma unroll
    for (int c = 0; c < NCHUNK; ++c) {
        const float P = oP[idx];
        const float Q = oQ[idx];
        const float R = oR[idx];
        const float S = oS[idx];
        idx += stride;
        acc = fmaf(R, h, acc) + S;
        h   = fmaf(P, h, Q);
    }

    // reduce over k (bits 0-3) then dir (bit 4) — all within a 32-lane group
    acc += __shfl_xor(acc, 1);
    acc += __shfl_xor(acc, 2);
    acc += __shfl_xor(acc, 4);
    acc += __shfl_xor(acc, 8);
    acc += __shfl_xor(acc, 16);

    if ((g & 31) == 0)
        out[n * DM + d] = acc * (1.0f / SEQ);
}

// ---------------------------------------------------------------------------
extern "C" void kernel_launch(void* const* d_in, const int* in_sizes, int n_in,
                              void* d_out, int out_size, void* d_ws, size_t ws_size,
                              hipStream_t stream) {
    const float* toks = (const float*)d_in[0];
    const float* logA = (const float*)d_in[1];
    const float* WB   = (const float*)d_in[2];
    const float* WC   = (const float*)d_in[3];
    const float* Wd   = (const float*)d_in[4];
    const float* bd   = (const float*)d_in[5];
    float* out = (float*)d_out;

    float* ws   = (float*)d_ws;
    float* wdd  = ws;                                    // 2*ROWS*DM
    float* wbc  = wdd + (size_t)2 * ROWS * DM;           // 2*ROWS*KS
    float* wP   = wbc + (size_t)2 * ROWS * KS;           // CH_TOT each
    float* wQ   = wP  + (size_t)CH_TOT;
    float* wR   = wQ  + (size_t)CH_TOT;
    float* wS   = wR  + (size_t)CH_TOT;

    k_gemm_delta<<<dim3(ROWS / GBM, DM / GBN), 256, 0, stream>>>(toks, Wd, bd, wdd);
    k_bc<<<ROWS / 16, 256, 0, stream>>>(toks, WB, WC, wbc);
    k_scan_chunk<<<(2 * NB * NCHUNK * DM * KS) / 256, 256, 0, stream>>>(
        wdd, wbc, logA, wP, wQ, wR, wS);
    k_scan_fix<<<(NB * DM * 32) / 256, 256, 0, stream>>>(wP, wQ, wR, wS, out);
}

// Round 16
// 301.977 us; speedup vs baseline: 1.0011x; 1.0011x over previous
//
#include <hip/hip_runtime.h>
#include <math.h>

#define NB   4
#define SEQ  2048
#define DM   512
#define KS   16
#define ROWS (NB*SEQ)   // 8192

#define NCHUNK 16
#define CLEN   (SEQ / NCHUNK)          // 128
#define CH_TOT (2 * NB * NCHUNK * DM * KS)   // 1,048,576 per array

typedef __attribute__((ext_vector_type(8))) short          bf16x8;
typedef __attribute__((ext_vector_type(8))) unsigned short u16x8;
typedef __attribute__((ext_vector_type(4))) float          f32x4;

__device__ __forceinline__ float softplus_f(float z) {
    return z > 20.f ? z : log1pf(__expf(z));
}

// f32 -> bf16 (RNE), bit-level (no NaN handling; inputs finite)
__device__ __forceinline__ unsigned short f2bf(float f) {
    unsigned int u = __builtin_bit_cast(unsigned int, f);
    u += 0x7fffu + ((u >> 16) & 1u);
    return (unsigned short)(u >> 16);
}

// ---------------------------------------------------------------------------
// Kernel 1: MFMA bf16 GEMM: d = softplus(toks@Wd^T + bd).
// Writes TIME-MAJOR packed float2 {delta, delta*x}:
//   odd[ ((n*DM + col)*SEQ + t) * 2 ]   with row = n*SEQ + t.
// 128x128 tile, 4 waves (2x2), wave tile 64x64, mfma_f32_16x16x32_bf16.
// Both A (toks) and B (Wd) staged f32 -> bf16 in registers.
// ---------------------------------------------------------------------------
#define GBM 128
#define GBN 128
#define GBK 32
#define PADK 40

__global__ __launch_bounds__(256)
void k_gemm_delta(const float* __restrict__ toks, const float* __restrict__ Wd,
                  const float* __restrict__ bd, float* __restrict__ odd)
{
    __shared__ unsigned short As[GBM][PADK];
    __shared__ unsigned short Bs[GBN][PADK];
    const int tid = threadIdx.x;
    const int rowBase = blockIdx.x * GBM;
    const int colBase = blockIdx.y * GBN;

    const int l   = tid & 63;
    const int wid = tid >> 6;          // 0..3
    const int wm  = wid >> 1;          // 0..1
    const int wn  = wid & 1;           // 0..1
    const int lr  = l & 15;            // A row / B col / D col lane part
    const int lk  = (l >> 4) * 8;      // frag k offset (8 contiguous bf16)
    const int lq  = (l >> 4) * 4;      // D row sub-offset

    // staging: 2 threads cover one row's 32 k
    const int srow  = tid >> 1;        // 0..127
    const int skoff = (tid & 1) * 16;  // 0 / 16

    const float* gA = toks + (size_t)(rowBase + srow) * DM + skoff;
    const float* gW = Wd   + (size_t)(colBase + srow) * DM + skoff;

    const f32x4 zero4 = {0.f, 0.f, 0.f, 0.f};
    f32x4 acc[4][4];
    #pragma unroll
    for (int i = 0; i < 4; ++i)
        #pragma unroll
        for (int j = 0; j < 4; ++j) acc[i][j] = zero4;

    // prefetch tile 0
    float4 pa0 = *(const float4*)(gA);
    float4 pa1 = *(const float4*)(gA + 4);
    float4 pa2 = *(const float4*)(gA + 8);
    float4 pa3 = *(const float4*)(gA + 12);
    float4 pw0 = *(const float4*)(gW);
    float4 pw1 = *(const float4*)(gW + 4);
    float4 pw2 = *(const float4*)(gW + 8);
    float4 pw3 = *(const float4*)(gW + 12);

    for (int e0 = 0; e0 < DM; e0 += GBK) {
        __syncthreads();   // previous iteration done reading LDS
        u16x8 va, vb, vc, vd;
        va[0] = f2bf(pa0.x); va[1] = f2bf(pa0.y); va[2] = f2bf(pa0.z); va[3] = f2bf(pa0.w);
        va[4] = f2bf(pa1.x); va[5] = f2bf(pa1.y); va[6] = f2bf(pa1.z); va[7] = f2bf(pa1.w);
        vb[0] = f2bf(pa2.x); vb[1] = f2bf(pa2.y); vb[2] = f2bf(pa2.z); vb[3] = f2bf(pa2.w);
        vb[4] = f2bf(pa3.x); vb[5] = f2bf(pa3.y); vb[6] = f2bf(pa3.z); vb[7] = f2bf(pa3.w);
        vc[0] = f2bf(pw0.x); vc[1] = f2bf(pw0.y); vc[2] = f2bf(pw0.z); vc[3] = f2bf(pw0.w);
        vc[4] = f2bf(pw1.x); vc[5] = f2bf(pw1.y); vc[6] = f2bf(pw1.z); vc[7] = f2bf(pw1.w);
        vd[0] = f2bf(pw2.x); vd[1] = f2bf(pw2.y); vd[2] = f2bf(pw2.z); vd[3] = f2bf(pw2.w);
        vd[4] = f2bf(pw3.x); vd[5] = f2bf(pw3.y); vd[6] = f2bf(pw3.z); vd[7] = f2bf(pw3.w);
        *(u16x8*)&As[srow][skoff]     = va;
        *(u16x8*)&As[srow][skoff + 8] = vb;
        *(u16x8*)&Bs[srow][skoff]     = vc;
        *(u16x8*)&Bs[srow][skoff + 8] = vd;
        __syncthreads();

        // prefetch next tile; latency hides under ds_reads + 16 MFMA
        if (e0 + GBK < DM) {
            pa0 = *(const float4*)(gA + e0 + GBK);
            pa1 = *(const float4*)(gA + e0 + GBK + 4);
            pa2 = *(const float4*)(gA + e0 + GBK + 8);
            pa3 = *(const float4*)(gA + e0 + GBK + 12);
            pw0 = *(const float4*)(gW + e0 + GBK);
            pw1 = *(const float4*)(gW + e0 + GBK + 4);
            pw2 = *(const float4*)(gW + e0 + GBK + 8);
            pw3 = *(const float4*)(gW + e0 + GBK + 12);
        }

        bf16x8 af[4], bfr[4];
        #pragma unroll
        for (int f = 0; f < 4; ++f)
            af[f] = *(const bf16x8*)&As[wm * 64 + f * 16 + lr][lk];
        #pragma unroll
        for (int f = 0; f < 4; ++f)
            bfr[f] = *(const bf16x8*)&Bs[wn * 64 + f * 16 + lr][lk];

        #pragma unroll
        for (int fm = 0; fm < 4; ++fm)
            #pragma unroll
            for (int fn = 0; fn < 4; ++fn)
                acc[fm][fn] = __builtin_amdgcn_mfma_f32_16x16x32_bf16(
                    af[fm], bfr[fn], acc[fm][fn], 0, 0, 0);
    }

    // epilogue: D lane mapping row=(l>>4)*4+r, col=l&15 (m89-verified).
    // time-major packed write. n is constant per block (SEQ % GBM == 0).
    const int nIdx = rowBase >> 11;            // rowBase / SEQ
    #pragma unroll
    for (int fn = 0; fn < 4; ++fn) {
        const int col = colBase + wn * 64 + fn * 16 + lr;
        const float bias = bd[col];
        float* cb = odd + 2 * ((size_t)(nIdx * DM + col) * SEQ);
        #pragma unroll
        for (int fm = 0; fm < 4; ++fm) {
            const int row0 = rowBase + wm * 64 + fm * 16 + lq;
            #pragma unroll
            for (int r = 0; r < 4; ++r) {
                const int row = row0 + r;
                const int t   = row & (SEQ - 1);
                const float dl = softplus_f(acc[fm][fn][r] + bias);
                *(float2*)&cb[2 * t] = make_float2(dl, dl * toks[(size_t)row * DM + col]);
            }
        }
    }
}

// ---------------------------------------------------------------------------
// Kernel 2: packed {B,C}: obc[2*(row*KS+k)] = toks@WB^T, +1 = toks@WC^T. f32.
// (t-adjacent rows are KS*2 floats apart: per-wave 128B contiguous, L2-hot.)
// ---------------------------------------------------------------------------
__global__ __launch_bounds__(256)
void k_bc(const float* __restrict__ toks, const float* __restrict__ WB,
          const float* __restrict__ WC, float* __restrict__ obc)
{
    const int tid = threadIdx.x;
    const int k  = tid & 15;
    const int rl = tid >> 4;
    const int row = blockIdx.x * 16 + rl;
    const float* tp = toks + (size_t)row * DM;
    const float* wb = WB + (size_t)k * DM;
    const float* wc = WC + (size_t)k * DM;
    float ab = 0.f, ac = 0.f;
    #pragma unroll 4
    for (int e = 0; e < DM; e += 4) {
        float4 tv = *(const float4*)(tp + e);
        float4 bv = *(const float4*)(wb + e);
        float4 cv = *(const float4*)(wc + e);
        ab = fmaf(tv.x, bv.x, ab); ab = fmaf(tv.y, bv.y, ab);
        ab = fmaf(tv.z, bv.z, ab); ab = fmaf(tv.w, bv.w, ab);
        ac = fmaf(tv.x, cv.x, ac); ac = fmaf(tv.y, cv.y, ac);
        ac = fmaf(tv.z, cv.z, ac); ac = fmaf(tv.w, cv.w, ac);
    }
    *(float2*)&obc[2 * ((size_t)row * KS + k)] = make_float2(ab, ac);
}

// ---------------------------------------------------------------------------
// Kernel 3a: chunked scan, pass 1. Thread = (dir,n,chunk,d,k).
// dd is TIME-MAJOR: per-thread CONTIGUOUS 8B steps (the layout fix).
// bc stays [n,t,k]: per-wave 128B contiguous per step, L2-resident.
// Chunk summary: h_end = P*h0 + Q ; sum_t c_t h_t = R*h0 + S.
// ---------------------------------------------------------------------------
__global__ __launch_bounds__(256)
void k_scan_chunk(const float* __restrict__ dd, const float* __restrict__ bc,
                  const float* __restrict__ logA,
                  float* __restrict__ oP, float* __restrict__ oQ,
                  float* __restrict__ oR, float* __restrict__ oS)
{
    const int g     = blockIdx.x * blockDim.x + threadIdx.x;
    const int k     = g & 15;
    const int d     = (g >> 4) & (DM - 1);
    const int chunk = (g >> 13) & (NCHUNK - 1);
    const int n     = (g >> 17) & (NB - 1);
    const int dir   = (g >> 19) & 1;

    const float Ac = -__expf(logA[d * KS + k]);

    const int sgn = dir ? -1 : 1;
    const int t0  = dir ? (SEQ - 1 - chunk * CLEN) : (chunk * CLEN);

    const float* pd = dd + 2 * ((size_t)(n * DM + d) * SEQ + t0);
    const float* pb = bc + 2 * (((size_t)n * SEQ + t0) * KS + k);
    const int sD = sgn * 2;
    const int sK = sgn * KS * 2;

    float A = 1.f, u = 0.f, R = 0.f, S = 0.f;
    #pragma unroll 4
    for (int t = 0; t < CLEN; ++t) {
        const float2 v = *(const float2*)pd;   // {delta, delta*x}
        const float2 w = *(const float2*)pb;   // {B, C}
        pd += sD; pb += sK;
        const float a = __expf(v.x * Ac);
        u = fmaf(a, u, v.y * w.x);
        A = A * a;
        R = fmaf(w.y, A, R);
        S = fmaf(w.y, u, S);
    }

    const size_t idx = ((((size_t)dir * NB + n) * NCHUNK + chunk) * DM + d) * KS + k;
    oP[idx] = A; oQ[idx] = u; oR[idx] = R; oS[idx] = S;
}

// ---------------------------------------------------------------------------
// Kernel 3b: compose chunk summaries; reduce over k (4 bits) + dir (1 bit)
// via shfl_xor within a 32-lane group; lane 0 stores directly (no atomic).
// ---------------------------------------------------------------------------
__global__ __launch_bounds__(256)
void k_scan_fix(const float* __restrict__ oP, const float* __restrict__ oQ,
                const float* __restrict__ oR, const float* __restrict__ oS,
                float* __restrict__ out)
{
    const int g    = blockIdx.x * blockDim.x + threadIdx.x;
    const int k    = g & 15;
    const int dir  = (g >> 4) & 1;
    const int d    = (g >> 5) & (DM - 1);
    const int n    = (g >> 14) & (NB - 1);

    size_t idx = ((((size_t)dir * NB + n) * NCHUNK) * DM + d) * KS + k;
    const size_t stride = (size_t)DM * KS;

    float h = 0.f, acc = 0.f;
    #pragma unroll
    for (int c = 0; c < NCHUNK; ++c) {
        const float P = oP[idx];
        const float Q = oQ[idx];
        const float R = oR[idx];
        const float S = oS[idx];
        idx += stride;
        acc = fmaf(R, h, acc) + S;
        h   = fmaf(P, h, Q);
    }

    acc += __shfl_xor(acc, 1);
    acc += __shfl_xor(acc, 2);
    acc += __shfl_xor(acc, 4);
    acc += __shfl_xor(acc, 8);
    acc += __shfl_xor(acc, 16);

    if ((g & 31) == 0)
        out[n * DM + d] = acc * (1.0f / SEQ);
}

// ---------------------------------------------------------------------------
extern "C" void kernel_launch(void* const* d_in, const int* in_sizes, int n_in,
                              void* d_out, int out_size, void* d_ws, size_t ws_size,
                              hipStream_t stream) {
    const float* toks = (const float*)d_in[0];
    const float* logA = (const float*)d_in[1];
    const float* WB   = (const float*)d_in[2];
    const float* WC   = (const float*)d_in[3];
    const float* Wd   = (const float*)d_in[4];
    const float* bd   = (const float*)d_in[5];
    float* out = (float*)d_out;

    float* ws   = (float*)d_ws;
    float* wdd  = ws;                                    // 2*ROWS*DM (time-major)
    float* wbc  = wdd + (size_t)2 * ROWS * DM;           // 2*ROWS*KS
    float* wP   = wbc + (size_t)2 * ROWS * KS;           // CH_TOT each
    float* wQ   = wP  + (size_t)CH_TOT;
    float* wR   = wQ  + (size_t)CH_TOT;
    float* wS   = wR  + (size_t)CH_TOT;

    k_gemm_delta<<<dim3(ROWS / GBM, DM / GBN), 256, 0, stream>>>(toks, Wd, bd, wdd);
    k_bc<<<ROWS / 16, 256, 0, stream>>>(toks, WB, WC, wbc);
    k_scan_chunk<<<(2 * NB * NCHUNK * DM * KS) / 256, 256, 0, stream>>>(
        wdd, wbc, logA, wP, wQ, wR, wS);
    k_scan_fix<<<(NB * DM * 32) / 256, 256, 0, stream>>>(wP, wQ, wR, wS, out);
}